// Round 1
// baseline (154.260 us; speedup 1.0000x reference)
//
#include <hip/hip_runtime.h>

// Morphological dilation2d on MI355X (gfx950).
// out[b,o,h,w] = max_{c,i,j} ( x_zpad[b,c,h+i-2,w+j-2] + weight[o,c,i,j] )
// B=4, C=4, O=4, H=W=1024, K=5, PAD=2, fp32.

constexpr int Himg = 1024, Wimg = 1024, Cin = 4, Cout = 4, Kn = 5;
constexpr int TH = 8, TW = 128;     // output tile per 256-thread block
constexpr int LR = TH + 4;          // 12 LDS rows (halo +-2)
constexpr int LC = TW + 8;          // 136 LDS cols (halo -4..+3 for aligned b128 window reads)
constexpr int LC4 = LC / 4;         // 34 float4 chunks per row

typedef float v2f __attribute__((ext_vector_type(2)));

// Re-layout weight [o][c][i][j] -> wt[c][i][j][o]  (float4 per (c,i,j) across o)
__global__ void reorg_w(const float* __restrict__ w, float* __restrict__ wt) {
  int idx = threadIdx.x;
  if (idx < Cout * Cin * Kn * Kn) {
    int o  = idx / (Cin * Kn * Kn);
    int r  = idx % (Cin * Kn * Kn);
    int c  = r / (Kn * Kn);
    int r2 = r % (Kn * Kn);
    int i  = r2 / Kn, j = r2 % Kn;
    wt[((c * Kn + i) * Kn + j) * Cout + o] = w[idx];
  }
}

// Fold 5 values with a tree so LLVM forms v_max3_f32 (2 instrs for 5 inputs).
__device__ __forceinline__ float max5(float a, float b, float c, float d, float e) {
  return fmaxf(fmaxf(a, b), fmaxf(c, fmaxf(d, e)));
}

template <bool TRANS>
__global__ __launch_bounds__(256) void morph(const float* __restrict__ x,
                                             const float* __restrict__ wt,
                                             float* __restrict__ out) {
  __shared__ __align__(16) float xs[Cin][LR][LC];
  const int tid = threadIdx.x;
  const int tile_w0 = blockIdx.x * TW;
  const int tile_r0 = blockIdx.y * TH;
  const int b = blockIdx.z;

  // ---- stage x tile (+halo, zero pad) into LDS, float4 coalesced ----
  for (int idx = tid; idx < Cin * LR * LC4; idx += 256) {
    const int c   = idx / (LR * LC4);
    const int rem = idx - c * (LR * LC4);
    const int row = rem / LC4;
    const int ch  = rem - row * LC4;
    const int gr  = tile_r0 - 2 + row;
    const int gc  = tile_w0 - 4 + ch * 4;
    float4 v = make_float4(0.f, 0.f, 0.f, 0.f);
    if ((unsigned)gr < (unsigned)Himg) {
      const float* src = x + ((size_t)(b * Cin + c) * Himg + gr) * Wimg;
      if (gc >= 0 && gc <= Wimg - 4) {
        v = *(const float4*)(src + gc);
      } else {
        if ((unsigned)(gc + 0) < (unsigned)Wimg) v.x = src[gc + 0];
        if ((unsigned)(gc + 1) < (unsigned)Wimg) v.y = src[gc + 1];
        if ((unsigned)(gc + 2) < (unsigned)Wimg) v.z = src[gc + 2];
        if ((unsigned)(gc + 3) < (unsigned)Wimg) v.w = src[gc + 3];
      }
    }
    *(float4*)&xs[c][row][ch * 4] = v;
  }
  __syncthreads();

  const int tx = tid & 31;   // 32 thread-cols x 4 px
  const int ty = tid >> 5;   // 8 rows

  float acc[Cout][4];
#pragma unroll
  for (int o = 0; o < Cout; ++o)
#pragma unroll
    for (int p = 0; p < 4; ++p) acc[o][p] = -3.4e38f;

// Per output-channel O: 10 packed adds (v_pk_add_f32) + 4 x (max5 tree + acc fold).
#define ACC_O(O, WA)                                                                     \
  do {                                                                                   \
    v2f p01[5], p23[5];                                                                  \
    _Pragma("unroll") for (int j = 0; j < 5; ++j) {                                      \
      v2f wb = {WA[j], WA[j]};                                                           \
      v2f a2 = {win[2 + j], win[3 + j]};                                                 \
      v2f b2 = {win[4 + j], win[5 + j]};                                                 \
      p01[j] = a2 + wb;                                                                  \
      p23[j] = b2 + wb;                                                                  \
    }                                                                                    \
    acc[O][0] = fmaxf(acc[O][0], max5(p01[0].x, p01[1].x, p01[2].x, p01[3].x, p01[4].x)); \
    acc[O][1] = fmaxf(acc[O][1], max5(p01[0].y, p01[1].y, p01[2].y, p01[3].y, p01[4].y)); \
    acc[O][2] = fmaxf(acc[O][2], max5(p23[0].x, p23[1].x, p23[2].x, p23[3].x, p23[4].x)); \
    acc[O][3] = fmaxf(acc[O][3], max5(p23[0].y, p23[1].y, p23[2].y, p23[3].y, p23[4].y)); \
  } while (0)

#pragma unroll 1
  for (int c = 0; c < Cin; ++c) {
#pragma unroll
    for (int i = 0; i < Kn; ++i) {
      const float* rowp = &xs[c][ty + i][tx * 4];
      float4 q0 = *(const float4*)(rowp);
      float4 q1 = *(const float4*)(rowp + 4);
      float4 q2 = *(const float4*)(rowp + 8);
      float win[12] = {q0.x, q0.y, q0.z, q0.w, q1.x, q1.y, q1.z, q1.w,
                       q2.x, q2.y, q2.z, q2.w};

      float wo0[5], wo1[5], wo2[5], wo3[5];
      if (TRANS) {
        const float4* wq = (const float4*)wt + (c * Kn + i) * Kn;
#pragma unroll
        for (int j = 0; j < Kn; ++j) {
          float4 wv = wq[j];
          wo0[j] = wv.x; wo1[j] = wv.y; wo2[j] = wv.z; wo3[j] = wv.w;
        }
      } else {
#pragma unroll
        for (int j = 0; j < Kn; ++j) {
          wo0[j] = wt[((0 * Cin + c) * Kn + i) * Kn + j];
          wo1[j] = wt[((1 * Cin + c) * Kn + i) * Kn + j];
          wo2[j] = wt[((2 * Cin + c) * Kn + i) * Kn + j];
          wo3[j] = wt[((3 * Cin + c) * Kn + i) * Kn + j];
        }
      }

      ACC_O(0, wo0);
      ACC_O(1, wo1);
      ACC_O(2, wo2);
      ACC_O(3, wo3);
    }
  }
#undef ACC_O

  // ---- epilogue: float4 stores, coalesced ----
  const int r = tile_r0 + ty;
  const int gc0 = tile_w0 + tx * 4;
#pragma unroll
  for (int o = 0; o < Cout; ++o) {
    float4 res = make_float4(acc[o][0], acc[o][1], acc[o][2], acc[o][3]);
    *(float4*)&out[((size_t)(b * Cout + o) * Himg + r) * Wimg + gc0] = res;
  }
}

extern "C" void kernel_launch(void* const* d_in, const int* in_sizes, int n_in,
                              void* d_out, int out_size, void* d_ws, size_t ws_size,
                              hipStream_t stream) {
  const float* x = (const float*)d_in[0];
  const float* w = (const float*)d_in[1];
  float* out = (float*)d_out;

  dim3 grid(Wimg / TW, Himg / TH, 4);  // (8, 128, 4)

  if (ws_size >= sizeof(float) * Cout * Cin * Kn * Kn) {
    float* wt = (float*)d_ws;
    reorg_w<<<dim3(1), dim3(512), 0, stream>>>(w, wt);
    morph<true><<<grid, dim3(256), 0, stream>>>(x, wt, out);
  } else {
    morph<false><<<grid, dim3(256), 0, stream>>>(x, w, out);
  }
}